// Round 3
// baseline (53.229 us; speedup 1.0000x reference)
//
#include <hip/hip_runtime.h>

#define INFV 3.0e38f
#define NBLOCKS 323
#define CNTBASE 0x7F7F7F7Fu

// ws layout (u32/float indices)
#define D1MIN 0        // 16*1024 final min d^2 via atomicMin (uint bitpattern)
#define D2MIN 16384    // 16*1024
#define CDMIN 32768    // 16*96 (padded 1536)
#define ACC   34304    // slots:
#define S_DIV  (ACC + 0)   // 16 per-batch div partials
#define S_DEL  (ACC + 16)  // 16 delta partials
#define S_POSE (ACC + 32)
#define S_NOCS (ACC + 33)
#define S_DIST (ACC + 34)
#define S_CNT  (ACC + 60)  // counter (u32), init 0x7F7F7F7F by ws_init
#define INIT_U32 34816     // 34 blocks * 256 thr * 4 u32

__device__ __forceinline__ float wave_reduce_sum(float v) {
#pragma unroll
    for (int m = 1; m < 64; m <<= 1) v += __shfl_xor(v, m);
    return v;
}

// returns full block sum to ALL threads (256-thread block)
__device__ __forceinline__ float block_sum_t0(float v, float* sbuf) {
    v = wave_reduce_sum(v);
    int lane = threadIdx.x & 63, wid = threadIdx.x >> 6;
    if (lane == 0) sbuf[wid] = v;
    __syncthreads();
    return sbuf[0] + sbuf[1] + sbuf[2] + sbuf[3];
}

__device__ __forceinline__ unsigned agent_load_u(const unsigned* p) {
    return __hip_atomic_load(p, __ATOMIC_RELAXED, __HIP_MEMORY_SCOPE_AGENT);
}
__device__ __forceinline__ float agent_load_f(const float* p) {
    return __hip_atomic_load(p, __ATOMIC_RELAXED, __HIP_MEMORY_SCOPE_AGENT);
}
__device__ __forceinline__ void agent_store_f(float* p, float v) {
    __hip_atomic_store(p, v, __ATOMIC_RELAXED, __HIP_MEMORY_SCOPE_AGENT);
}

// pc_mask may arrive as u8 (1B) or i32 (4B). Probe bytes at 4i+1 (wave-wide).
__device__ __forceinline__ bool mask_mode_u8(const void* mp) {
    const unsigned char* p = (const unsigned char*)mp;
    unsigned char v = p[(threadIdx.x & 63) * 4 + 1];
    return __ballot(v != 0) != 0ull;
}
__device__ __forceinline__ bool mask_at(const void* mp, int idx, bool u8) {
    if (u8) return ((const unsigned char*)mp)[idx] != 0;
    return ((const int*)mp)[idx] != 0;
}

__global__ __launch_bounds__(256) void ws_init(uint4* __restrict__ p) {
    p[blockIdx.x * 256 + threadIdx.x] =
        make_uint4(CNTBASE, CNTBASE, CNTBASE, CNTBASE);
}

__global__ __launch_bounds__(256) void loss_main(
    const float* __restrict__ pts,          // (16,1024,3)
    const float* __restrict__ recon_delta,  // (16,1024,3)
    const float* __restrict__ kpt,          // (16,96,3)
    const float* __restrict__ recon,        // (16,1024,3)
    const float* __restrict__ t_label,      // (16,3)
    const float* __restrict__ r_label,      // (16,3,3)
    const float* __restrict__ s_label,      // (16,3)
    const float* __restrict__ pred_r,       // (16,3,3)
    const float* __restrict__ pred_t,       // (16,3)
    const float* __restrict__ pred_s,       // (16,3)
    const float* __restrict__ kpt_nocs,     // (16,96,3)
    const void*  __restrict__ pc_mask,      // (16,1024) bool
    const float* __restrict__ d_pn,         // (16,512)
    const float* __restrict__ d_ul,         // (16,512)
    float* __restrict__ ws,
    float* __restrict__ out)
{
    __shared__ float4 lds4[512];
    __shared__ float sbuf[8];
    __shared__ float red[16];
    __shared__ unsigned lastFlag;
    const int t = threadIdx.x;
    const int blk = blockIdx.x;

    if (blk < 128) {
        // ---- d1: block=(b,jc). Stage 128 recon pts (float4); thread owns 4 pts.
        int b = blk >> 3, jc = blk & 7;
        if (t < 128) {
            const float* g = recon + ((b << 10) + jc * 128 + t) * 3;
            lds4[t] = make_float4(g[0], g[1], g[2], 0.0f);
        }
        __syncthreads();
        float px[4], py[4], pz[4], dmin[4];
#pragma unroll
        for (int p = 0; p < 4; ++p) {
            const float* P = pts + ((b << 10) + t + (p << 8)) * 3;
            px[p] = P[0]; py[p] = P[1]; pz[p] = P[2];
            dmin[p] = INFV;
        }
#pragma unroll 4
        for (int j = 0; j < 128; ++j) {
            float4 r = lds4[j];
#pragma unroll
            for (int p = 0; p < 4; ++p) {
                float dx = px[p] - r.x, dy = py[p] - r.y, dz = pz[p] - r.z;
                dmin[p] = fminf(dmin[p], dx * dx + dy * dy + dz * dz);
            }
        }
        unsigned* dst = (unsigned*)ws + D1MIN + (b << 10);
#pragma unroll
        for (int p = 0; p < 4; ++p)
            atomicMin(dst + t + (p << 8), __float_as_uint(dmin[p]));

    } else if (blk < 256) {
        // ---- d2: block=(b,ic). Stage 128 pts masked->1e18; thread owns 4 recon.
        int bb = blk - 128;
        int b = bb >> 3, ic = bb & 7;
        bool u8 = mask_mode_u8(pc_mask);
        if (t < 128) {
            int i = ic * 128 + t;
            const float* P = pts + ((b << 10) + i) * 3;
            bool m = mask_at(pc_mask, (b << 10) + i, u8);
            lds4[t] = m ? make_float4(P[0], P[1], P[2], 0.0f)
                        : make_float4(1e18f, 1e18f, 1e18f, 0.0f);
        }
        __syncthreads();
        float rx[4], ry[4], rz[4], dmin[4];
#pragma unroll
        for (int p = 0; p < 4; ++p) {
            const float* R = recon + ((b << 10) + t + (p << 8)) * 3;
            rx[p] = R[0]; ry[p] = R[1]; rz[p] = R[2];
            dmin[p] = INFV;
        }
#pragma unroll 4
        for (int i = 0; i < 128; ++i) {
            float4 q = lds4[i];
#pragma unroll
            for (int p = 0; p < 4; ++p) {
                float dx = rx[p] - q.x, dy = ry[p] - q.y, dz = rz[p] - q.z;
                dmin[p] = fminf(dmin[p], dx * dx + dy * dy + dz * dz);
            }
        }
        unsigned* dst = (unsigned*)ws + D2MIN + (b << 10);
#pragma unroll
        for (int p = 0; p < 4; ++p)
            atomicMin(dst + t + (p << 8), __float_as_uint(dmin[p]));

    } else if (blk < 288) {
        // ---- cd: block=(b, half). Stage 512 pts; t<192 -> (quarter q, k).
        int bb = blk - 256;
        int b = bb >> 1, ih = bb & 1;
        const float* src = pts + ((b << 10) + ih * 512) * 3;
        for (int e = t; e < 512; e += 256) {
            const float* g = src + e * 3;
            lds4[e] = make_float4(g[0], g[1], g[2], 0.0f);
        }
        __syncthreads();
        if (t < 192) {
            int q = t / 96, k = t - q * 96;
            const float* K = kpt + (b * 96 + k) * 3;
            float kx = K[0], ky = K[1], kz = K[2];
            float dmin = INFV;
            int base = q << 8;
#pragma unroll 4
            for (int i = 0; i < 256; ++i) {
                float4 p4 = lds4[base + i];
                float dx = kx - p4.x, dy = ky - p4.y, dz = kz - p4.z;
                dmin = fminf(dmin, dx * dx + dy * dy + dz * dz);
            }
            atomicMin((unsigned*)ws + CDMIN + b * 96 + k, __float_as_uint(dmin));
        }

    } else if (blk < 304) {
        // ---- diversity per batch
        int b = blk - 288;
        const float* K = kpt + b * 288;
        if (t < 96) lds4[t] = make_float4(K[t * 3], K[t * 3 + 1], K[t * 3 + 2], 0.0f);
        __syncthreads();
        float acc = 0.0f;
        for (int r = 0; r < 36; ++r) {
            int p = r * 256 + t;
            int ki = p / 96, kj = p - ki * 96;
            float4 a = lds4[ki], c = lds4[kj];
            float dx = a.x - c.x, dy = a.y - c.y, dz = a.z - c.z;
            float d = sqrtf(dx * dx + dy * dy + dz * dz + 1e-12f);
            if (ki != kj && d < 0.1f) acc += 1.0f - d * 10.0f;
        }
        float s = block_sum_t0(acc, sbuf);
        if (t == 0) agent_store_f(ws + S_DIV + b, s);

    } else if (blk < 320) {
        // ---- recon_delta norms
        int e = blk - 304;
        float acc = 0.0f;
#pragma unroll
        for (int r = 0; r < 4; ++r) {
            const float* D = recon_delta + (e * 1024 + r * 256 + t) * 3;
            acc += sqrtf(D[0] * D[0] + D[1] * D[1] + D[2] * D[2]);
        }
        float s = block_sum_t0(acc, sbuf);
        if (t == 0) agent_store_f(ws + S_DEL + (blk - 304), s);

    } else if (blk == 320) {
        // ---- pose (fully normalized)
        float c = 0.0f;
        if (t < 48) {
            int b = t / 3, j = t - b * 3;
            float s = 0.0f;
#pragma unroll
            for (int i2 = 0; i2 < 3; ++i2) {
                float d = pred_r[b * 9 + i2 * 3 + j] - r_label[b * 9 + i2 * 3 + j];
                s += d * d;
            }
            c = sqrtf(s) * (1.0f / 48.0f);
        } else if (t >= 64 && t < 80) {
            int b = t - 64;
            float s = 0.0f;
#pragma unroll
            for (int d2i = 0; d2i < 3; ++d2i) {
                float d = pred_t[b * 3 + d2i] - t_label[b * 3 + d2i];
                s += d * d;
            }
            c = sqrtf(s) * (1.0f / 16.0f);
        } else if (t >= 96 && t < 112) {
            int b = t - 96;
            float s = 0.0f;
#pragma unroll
            for (int d2i = 0; d2i < 3; ++d2i) {
                float d = pred_s[b * 3 + d2i] - s_label[b * 3 + d2i];
                s += d * d;
            }
            c = sqrtf(s) * (1.0f / 16.0f);
        }
        float s = block_sum_t0(c, sbuf);
        if (t == 0) agent_store_f(ws + S_POSE, s);

    } else if (blk == 321) {
        // ---- NOCS smooth-L1
        float acc = 0.0f;
#pragma unroll
        for (int r = 0; r < 6; ++r) {
            int item = r * 256 + t;
            int b = item / 96, k = item - b * 96;
            float sx = s_label[b * 3], sy = s_label[b * 3 + 1], sz = s_label[b * 3 + 2];
            float sn = sqrtf(sx * sx + sy * sy + sz * sz) + 1e-8f;
            float v0 = (kpt[(b * 96 + k) * 3 + 0] - t_label[b * 3 + 0]) / sn;
            float v1 = (kpt[(b * 96 + k) * 3 + 1] - t_label[b * 3 + 1]) / sn;
            float v2 = (kpt[(b * 96 + k) * 3 + 2] - t_label[b * 3 + 2]) / sn;
#pragma unroll
            for (int e = 0; e < 3; ++e) {
                float gt = v0 * r_label[b * 9 + e] + v1 * r_label[b * 9 + 3 + e] +
                           v2 * r_label[b * 9 + 6 + e];
                float diff = fabsf(kpt_nocs[(b * 96 + k) * 3 + e] - gt);
                acc += (diff > 0.1f) ? (diff - 0.05f) : (diff * diff * 5.0f);
            }
        }
        float s = block_sum_t0(acc, sbuf);
        if (t == 0) agent_store_f(ws + S_NOCS, s);

    } else {
        // ---- distillation
        int b = t >> 4, off = t & 15;
        float s = 0.0f;
        for (int c2 = off; c2 < 512; c2 += 16) {
            float d = d_pn[b * 512 + c2] - d_ul[b * 512 + c2];
            s += d * d;
        }
        s += __shfl_xor(s, 1);
        s += __shfl_xor(s, 2);
        s += __shfl_xor(s, 4);
        s += __shfl_xor(s, 8);
        float c = (off == 0) ? sqrtf(s) : 0.0f;
        float sm = block_sum_t0(c, sbuf);
        if (t == 0) agent_store_f(ws + S_DIST, sm);
    }

    // ---- last-block gate
    __syncthreads();
    if (t == 0) {
        __threadfence();
        unsigned old = atomicAdd((unsigned*)ws + S_CNT, 1u);
        lastFlag = ((old - CNTBASE) == (NBLOCKS - 1)) ? 1u : 0u;
    }
    __syncthreads();
    if (!lastFlag) return;
    __threadfence();

    // ================= phase 2 (single block) =================
    bool u8 = mask_mode_u8(pc_mask);

    // d1 per-b masked mean: 16 threads per b
    int b16 = t >> 4, l16 = t & 15;
    float s1 = 0.0f, s2 = 0.0f;
    const unsigned* mp1 = (const unsigned*)ws + D1MIN + (b16 << 10);
    for (int r = 0; r < 64; ++r) {
        int i = l16 + (r << 4);
        unsigned um = agent_load_u(mp1 + i);
        if (mask_at(pc_mask, (b16 << 10) + i, u8)) {
            s1 += sqrtf(__uint_as_float(um));
            s2 += 1.0f;
        }
    }
#pragma unroll
    for (int m = 1; m < 16; m <<= 1) {
        s1 += __shfl_xor(s1, m);
        s2 += __shfl_xor(s2, m);
    }
    if (l16 == 0) red[b16] = 0.5f * s1 / s2;

    // d2 total
    float sA = 0.0f;
    const unsigned* mp2 = (const unsigned*)ws + D2MIN;
    for (int r = 0; r < 64; ++r)
        sA += sqrtf(__uint_as_float(agent_load_u(mp2 + t + (r << 8))));
    // cd total
    float sC = 0.0f;
    const unsigned* mp3 = (const unsigned*)ws + CDMIN;
#pragma unroll
    for (int r = 0; r < 6; ++r)
        sC += sqrtf(__uint_as_float(agent_load_u(mp3 + t + (r << 8))));

    sA = wave_reduce_sum(sA);
    sC = wave_reduce_sum(sC);
    int lane = t & 63, wid = t >> 6;
    if (lane == 0) { sbuf[wid] = sA; sbuf[4 + wid] = sC; }
    __syncthreads();

    if (t == 0) {
        float d2sum = sbuf[0] + sbuf[1] + sbuf[2] + sbuf[3];
        float cdsum = sbuf[4] + sbuf[5] + sbuf[6] + sbuf[7];
        float d1part = 0.0f;
#pragma unroll
        for (int b = 0; b < 16; ++b) d1part += red[b];
        float divs = 0.0f, dels = 0.0f;
#pragma unroll
        for (int q = 0; q < 16; ++q) {
            divs += agent_load_f(ws + S_DIV + q);
            dels += agent_load_f(ws + S_DEL + q);
        }
        float pose  = agent_load_f(ws + S_POSE);
        float nocs  = agent_load_f(ws + S_NOCS) * (1.0f / 1536.0f);
        float dist  = agent_load_f(ws + S_DIST) * (1.0f / 16.0f);
        float recon = d1part * (1.0f / 16.0f) + 0.5f * d2sum * (1.0f / 16384.0f);
        float cd    = cdsum * (1.0f / 1536.0f);
        float divl  = divs * (1.0f / (9120.0f * 16.0f));
        float delta = dels * (1.0f / 16384.0f);
        float all = pose + nocs + cd + divl + recon + delta + dist;
        out[0] = all;  out[1] = pose;  out[2] = nocs;  out[3] = cd;
        out[4] = divl; out[5] = recon; out[6] = delta; out[7] = dist;
    }
}

extern "C" void kernel_launch(void* const* d_in, const int* in_sizes, int n_in,
                              void* d_out, int out_size, void* d_ws, size_t ws_size,
                              hipStream_t stream) {
    float* ws = (float*)d_ws;
    ws_init<<<INIT_U32 / (256 * 4), 256, 0, stream>>>((uint4*)d_ws);
    loss_main<<<NBLOCKS, 256, 0, stream>>>(
        (const float*)d_in[0],  (const float*)d_in[1],  (const float*)d_in[2],
        (const float*)d_in[3],  (const float*)d_in[4],  (const float*)d_in[5],
        (const float*)d_in[6],  (const float*)d_in[7],  (const float*)d_in[8],
        (const float*)d_in[9],  (const float*)d_in[10], (const void*)d_in[11],
        (const float*)d_in[12], (const float*)d_in[13], ws, (float*)d_out);
}

// Round 4
// 38.157 us; speedup vs baseline: 1.3950x; 1.3950x over previous
//
#include <hip/hip_runtime.h>

#define INFV 3.0e38f
#define NBLOCKS 323
#define CNTBASE 0x7F7F7F7Fu

// ws layout (u32/float indices)
#define D1MIN 0        // 16*1024 final min d^2 via atomicMin (uint bitpattern)
#define D2MIN 16384    // 16*1024
#define CDMIN 32768    // 16*96 (padded 1536)
#define ACC   34304    // slots:
#define S_DIV  (ACC + 0)   // 16 per-batch div partials
#define S_DEL  (ACC + 16)  // 16 delta partials
#define S_POSE (ACC + 32)
#define S_NOCS (ACC + 33)
#define S_DIST (ACC + 34)
#define S_CNT  (ACC + 60)  // counter (u32), init CNTBASE by ws_init each call
#define INIT_U32 34816     // 34 blocks * 256 thr * 4 u32

__device__ __forceinline__ float wave_reduce_sum(float v) {
#pragma unroll
    for (int m = 1; m < 64; m <<= 1) v += __shfl_xor(v, m);
    return v;
}

// returns full block sum to ALL threads (256-thread block)
__device__ __forceinline__ float block_sum_t0(float v, float* sbuf) {
    v = wave_reduce_sum(v);
    int lane = threadIdx.x & 63, wid = threadIdx.x >> 6;
    if (lane == 0) sbuf[wid] = v;
    __syncthreads();
    return sbuf[0] + sbuf[1] + sbuf[2] + sbuf[3];
}

__device__ __forceinline__ float agent_load_f(const float* p) {
    return __hip_atomic_load(p, __ATOMIC_RELAXED, __HIP_MEMORY_SCOPE_AGENT);
}
__device__ __forceinline__ void agent_store_f(float* p, float v) {
    __hip_atomic_store(p, v, __ATOMIC_RELAXED, __HIP_MEMORY_SCOPE_AGENT);
}

// pc_mask may arrive as u8 (1B) or i32 (4B). Probe bytes at 4i+1 (wave-wide).
__device__ __forceinline__ bool mask_mode_u8(const void* mp) {
    const unsigned char* p = (const unsigned char*)mp;
    unsigned char v = p[(threadIdx.x & 63) * 4 + 1];
    return __ballot(v != 0) != 0ull;
}
__device__ __forceinline__ bool mask_at(const void* mp, int idx, bool u8) {
    if (u8) return ((const unsigned char*)mp)[idx] != 0;
    return ((const int*)mp)[idx] != 0;
}

__global__ __launch_bounds__(256) void ws_init(uint4* __restrict__ p) {
    p[blockIdx.x * 256 + threadIdx.x] =
        make_uint4(CNTBASE, CNTBASE, CNTBASE, CNTBASE);
}

__global__ __launch_bounds__(256) void loss_main(
    const float* __restrict__ pts,          // (16,1024,3)
    const float* __restrict__ recon_delta,  // (16,1024,3)
    const float* __restrict__ kpt,          // (16,96,3)
    const float* __restrict__ recon,        // (16,1024,3)
    const float* __restrict__ t_label,      // (16,3)
    const float* __restrict__ r_label,      // (16,3,3)
    const float* __restrict__ s_label,      // (16,3)
    const float* __restrict__ pred_r,       // (16,3,3)
    const float* __restrict__ pred_t,       // (16,3)
    const float* __restrict__ pred_s,       // (16,3)
    const float* __restrict__ kpt_nocs,     // (16,96,3)
    const void*  __restrict__ pc_mask,      // (16,1024) bool
    const float* __restrict__ d_pn,         // (16,512)
    const float* __restrict__ d_ul,         // (16,512)
    float* __restrict__ ws,
    float* __restrict__ out)
{
    __shared__ float4 lds4[512];
    __shared__ float sbuf[8];
    __shared__ float red[16];
    __shared__ unsigned lastFlag;
    const int t = threadIdx.x;
    const int blk = blockIdx.x;

    if (blk < 128) {
        // ---- d1: block=(b,jc). Stage 128 recon pts (float4); thread owns 4 pts.
        int b = blk >> 3, jc = blk & 7;
        if (t < 128) {
            const float* g = recon + ((b << 10) + jc * 128 + t) * 3;
            lds4[t] = make_float4(g[0], g[1], g[2], 0.0f);
        }
        __syncthreads();
        float px[4], py[4], pz[4], dmin[4];
#pragma unroll
        for (int p = 0; p < 4; ++p) {
            const float* P = pts + ((b << 10) + t + (p << 8)) * 3;
            px[p] = P[0]; py[p] = P[1]; pz[p] = P[2];
            dmin[p] = INFV;
        }
#pragma unroll 4
        for (int j = 0; j < 128; ++j) {
            float4 r = lds4[j];
#pragma unroll
            for (int p = 0; p < 4; ++p) {
                float dx = px[p] - r.x, dy = py[p] - r.y, dz = pz[p] - r.z;
                dmin[p] = fminf(dmin[p], dx * dx + dy * dy + dz * dz);
            }
        }
        unsigned* dst = (unsigned*)ws + D1MIN + (b << 10);
#pragma unroll
        for (int p = 0; p < 4; ++p)
            atomicMin(dst + t + (p << 8), __float_as_uint(dmin[p]));

    } else if (blk < 256) {
        // ---- d2: block=(b,ic). Stage 128 pts masked->1e18; thread owns 4 recon.
        int bb = blk - 128;
        int b = bb >> 3, ic = bb & 7;
        bool u8 = mask_mode_u8(pc_mask);
        if (t < 128) {
            int i = ic * 128 + t;
            const float* P = pts + ((b << 10) + i) * 3;
            bool m = mask_at(pc_mask, (b << 10) + i, u8);
            lds4[t] = m ? make_float4(P[0], P[1], P[2], 0.0f)
                        : make_float4(1e18f, 1e18f, 1e18f, 0.0f);
        }
        __syncthreads();
        float rx[4], ry[4], rz[4], dmin[4];
#pragma unroll
        for (int p = 0; p < 4; ++p) {
            const float* R = recon + ((b << 10) + t + (p << 8)) * 3;
            rx[p] = R[0]; ry[p] = R[1]; rz[p] = R[2];
            dmin[p] = INFV;
        }
#pragma unroll 4
        for (int i = 0; i < 128; ++i) {
            float4 q = lds4[i];
#pragma unroll
            for (int p = 0; p < 4; ++p) {
                float dx = rx[p] - q.x, dy = ry[p] - q.y, dz = rz[p] - q.z;
                dmin[p] = fminf(dmin[p], dx * dx + dy * dy + dz * dz);
            }
        }
        unsigned* dst = (unsigned*)ws + D2MIN + (b << 10);
#pragma unroll
        for (int p = 0; p < 4; ++p)
            atomicMin(dst + t + (p << 8), __float_as_uint(dmin[p]));

    } else if (blk < 288) {
        // ---- cd: block=(b, half). Stage 512 pts; t<192 -> (quarter q, k).
        int bb = blk - 256;
        int b = bb >> 1, ih = bb & 1;
        const float* src = pts + ((b << 10) + ih * 512) * 3;
        for (int e = t; e < 512; e += 256) {
            const float* g = src + e * 3;
            lds4[e] = make_float4(g[0], g[1], g[2], 0.0f);
        }
        __syncthreads();
        if (t < 192) {
            int q = t / 96, k = t - q * 96;
            const float* K = kpt + (b * 96 + k) * 3;
            float kx = K[0], ky = K[1], kz = K[2];
            float dmin = INFV;
            int base = q << 8;
#pragma unroll 4
            for (int i = 0; i < 256; ++i) {
                float4 p4 = lds4[base + i];
                float dx = kx - p4.x, dy = ky - p4.y, dz = kz - p4.z;
                dmin = fminf(dmin, dx * dx + dy * dy + dz * dz);
            }
            atomicMin((unsigned*)ws + CDMIN + b * 96 + k, __float_as_uint(dmin));
        }

    } else if (blk < 304) {
        // ---- diversity per batch
        int b = blk - 288;
        const float* K = kpt + b * 288;
        if (t < 96) lds4[t] = make_float4(K[t * 3], K[t * 3 + 1], K[t * 3 + 2], 0.0f);
        __syncthreads();
        float acc = 0.0f;
        for (int r = 0; r < 36; ++r) {
            int p = r * 256 + t;
            int ki = p / 96, kj = p - ki * 96;
            float4 a = lds4[ki], c = lds4[kj];
            float dx = a.x - c.x, dy = a.y - c.y, dz = a.z - c.z;
            float d = sqrtf(dx * dx + dy * dy + dz * dz + 1e-12f);
            if (ki != kj && d < 0.1f) acc += 1.0f - d * 10.0f;
        }
        float s = block_sum_t0(acc, sbuf);
        if (t == 0) agent_store_f(ws + S_DIV + b, s);

    } else if (blk < 320) {
        // ---- recon_delta norms
        int e = blk - 304;
        float acc = 0.0f;
#pragma unroll
        for (int r = 0; r < 4; ++r) {
            const float* D = recon_delta + (e * 1024 + r * 256 + t) * 3;
            acc += sqrtf(D[0] * D[0] + D[1] * D[1] + D[2] * D[2]);
        }
        float s = block_sum_t0(acc, sbuf);
        if (t == 0) agent_store_f(ws + S_DEL + (blk - 304), s);

    } else if (blk == 320) {
        // ---- pose (fully normalized)
        float c = 0.0f;
        if (t < 48) {
            int b = t / 3, j = t - b * 3;
            float s = 0.0f;
#pragma unroll
            for (int i2 = 0; i2 < 3; ++i2) {
                float d = pred_r[b * 9 + i2 * 3 + j] - r_label[b * 9 + i2 * 3 + j];
                s += d * d;
            }
            c = sqrtf(s) * (1.0f / 48.0f);
        } else if (t >= 64 && t < 80) {
            int b = t - 64;
            float s = 0.0f;
#pragma unroll
            for (int d2i = 0; d2i < 3; ++d2i) {
                float d = pred_t[b * 3 + d2i] - t_label[b * 3 + d2i];
                s += d * d;
            }
            c = sqrtf(s) * (1.0f / 16.0f);
        } else if (t >= 96 && t < 112) {
            int b = t - 96;
            float s = 0.0f;
#pragma unroll
            for (int d2i = 0; d2i < 3; ++d2i) {
                float d = pred_s[b * 3 + d2i] - s_label[b * 3 + d2i];
                s += d * d;
            }
            c = sqrtf(s) * (1.0f / 16.0f);
        }
        float s = block_sum_t0(c, sbuf);
        if (t == 0) agent_store_f(ws + S_POSE, s);

    } else if (blk == 321) {
        // ---- NOCS smooth-L1
        float acc = 0.0f;
#pragma unroll
        for (int r = 0; r < 6; ++r) {
            int item = r * 256 + t;
            int b = item / 96, k = item - b * 96;
            float sx = s_label[b * 3], sy = s_label[b * 3 + 1], sz = s_label[b * 3 + 2];
            float sn = sqrtf(sx * sx + sy * sy + sz * sz) + 1e-8f;
            float v0 = (kpt[(b * 96 + k) * 3 + 0] - t_label[b * 3 + 0]) / sn;
            float v1 = (kpt[(b * 96 + k) * 3 + 1] - t_label[b * 3 + 1]) / sn;
            float v2 = (kpt[(b * 96 + k) * 3 + 2] - t_label[b * 3 + 2]) / sn;
#pragma unroll
            for (int e = 0; e < 3; ++e) {
                float gt = v0 * r_label[b * 9 + e] + v1 * r_label[b * 9 + 3 + e] +
                           v2 * r_label[b * 9 + 6 + e];
                float diff = fabsf(kpt_nocs[(b * 96 + k) * 3 + e] - gt);
                acc += (diff > 0.1f) ? (diff - 0.05f) : (diff * diff * 5.0f);
            }
        }
        float s = block_sum_t0(acc, sbuf);
        if (t == 0) agent_store_f(ws + S_NOCS, s);

    } else {
        // ---- distillation
        int b = t >> 4, off = t & 15;
        float s = 0.0f;
        for (int c2 = off; c2 < 512; c2 += 16) {
            float d = d_pn[b * 512 + c2] - d_ul[b * 512 + c2];
            s += d * d;
        }
        s += __shfl_xor(s, 1);
        s += __shfl_xor(s, 2);
        s += __shfl_xor(s, 4);
        s += __shfl_xor(s, 8);
        float c = (off == 0) ? sqrtf(s) : 0.0f;
        float sm = block_sum_t0(c, sbuf);
        if (t == 0) agent_store_f(ws + S_DIST, sm);
    }

    // ---- last-block gate (release: threadfence + atomicAdd)
    __syncthreads();
    if (t == 0) {
        __threadfence();
        unsigned old = atomicAdd((unsigned*)ws + S_CNT, 1u);
        lastFlag = ((old - CNTBASE) == (NBLOCKS - 1)) ? 1u : 0u;
    }
    __syncthreads();
    if (!lastFlag) return;
    __threadfence();   // acquire: invalidate L1 so plain loads see L2-final values

    // ================= phase 2 (single block), plain vectorized loads =========
    bool u8 = mask_mode_u8(pc_mask);

    // d1 per-batch masked mean: 16 threads per batch, uint4 loads
    int b16 = t >> 4, l16 = t & 15;
    float s1 = 0.0f, s2 = 0.0f;
    const uint4* w4 = (const uint4*)ws;          // D1MIN == 0
#pragma unroll
    for (int r = 0; r < 16; ++r) {
        int idx4 = (b16 << 8) + (r << 4) + l16;  // uint4 index
        uint4 v = w4[idx4];
        int e = idx4 << 2;                        // element index
        unsigned m0, m1, m2, m3;
        if (u8) {
            unsigned mb = *(const unsigned*)((const unsigned char*)pc_mask + e);
            m0 = mb & 0xffu; m1 = (mb >> 8) & 0xffu;
            m2 = (mb >> 16) & 0xffu; m3 = mb >> 24;
        } else {
            uint4 mi = ((const uint4*)pc_mask)[idx4];
            m0 = mi.x; m1 = mi.y; m2 = mi.z; m3 = mi.w;
        }
        if (m0) { s1 += sqrtf(__uint_as_float(v.x)); s2 += 1.0f; }
        if (m1) { s1 += sqrtf(__uint_as_float(v.y)); s2 += 1.0f; }
        if (m2) { s1 += sqrtf(__uint_as_float(v.z)); s2 += 1.0f; }
        if (m3) { s1 += sqrtf(__uint_as_float(v.w)); s2 += 1.0f; }
    }
#pragma unroll
    for (int m = 1; m < 16; m <<= 1) {
        s1 += __shfl_xor(s1, m);
        s2 += __shfl_xor(s2, m);
    }
    if (l16 == 0) red[b16] = 0.5f * s1 / s2;

    // d2 total: uint4 loads, lane-contiguous
    float sA = 0.0f;
    const uint4* w4d2 = (const uint4*)(ws + D2MIN);
#pragma unroll
    for (int r = 0; r < 16; ++r) {
        uint4 v = w4d2[(r << 8) + t];
        sA += sqrtf(__uint_as_float(v.x)) + sqrtf(__uint_as_float(v.y)) +
              sqrtf(__uint_as_float(v.z)) + sqrtf(__uint_as_float(v.w));
    }
    // cd total: 1536 elements = 256*uint4 + 256*uint2
    float sC = 0.0f;
    {
        uint4 v = ((const uint4*)(ws + CDMIN))[t];
        sC += sqrtf(__uint_as_float(v.x)) + sqrtf(__uint_as_float(v.y)) +
              sqrtf(__uint_as_float(v.z)) + sqrtf(__uint_as_float(v.w));
        uint2 v2 = ((const uint2*)(ws + CDMIN + 1024))[t];
        sC += sqrtf(__uint_as_float(v2.x)) + sqrtf(__uint_as_float(v2.y));
    }

    sA = wave_reduce_sum(sA);
    sC = wave_reduce_sum(sC);
    int lane = t & 63, wid = t >> 6;
    if (lane == 0) { sbuf[wid] = sA; sbuf[4 + wid] = sC; }
    __syncthreads();

    if (t == 0) {
        float d2sum = sbuf[0] + sbuf[1] + sbuf[2] + sbuf[3];
        float cdsum = sbuf[4] + sbuf[5] + sbuf[6] + sbuf[7];
        float d1part = 0.0f;
#pragma unroll
        for (int b = 0; b < 16; ++b) d1part += red[b];
        float divs = 0.0f, dels = 0.0f;
#pragma unroll
        for (int q = 0; q < 16; ++q) {
            divs += agent_load_f(ws + S_DIV + q);
            dels += agent_load_f(ws + S_DEL + q);
        }
        float pose  = agent_load_f(ws + S_POSE);
        float nocs  = agent_load_f(ws + S_NOCS) * (1.0f / 1536.0f);
        float dist  = agent_load_f(ws + S_DIST) * (1.0f / 16.0f);
        float recon = d1part * (1.0f / 16.0f) + 0.5f * d2sum * (1.0f / 16384.0f);
        float cd    = cdsum * (1.0f / 1536.0f);
        float divl  = divs * (1.0f / (9120.0f * 16.0f));
        float delta = dels * (1.0f / 16384.0f);
        float all = pose + nocs + cd + divl + recon + delta + dist;
        out[0] = all;  out[1] = pose;  out[2] = nocs;  out[3] = cd;
        out[4] = divl; out[5] = recon; out[6] = delta; out[7] = dist;
    }
}

extern "C" void kernel_launch(void* const* d_in, const int* in_sizes, int n_in,
                              void* d_out, int out_size, void* d_ws, size_t ws_size,
                              hipStream_t stream) {
    float* ws = (float*)d_ws;
    ws_init<<<INIT_U32 / (256 * 4), 256, 0, stream>>>((uint4*)d_ws);
    loss_main<<<NBLOCKS, 256, 0, stream>>>(
        (const float*)d_in[0],  (const float*)d_in[1],  (const float*)d_in[2],
        (const float*)d_in[3],  (const float*)d_in[4],  (const float*)d_in[5],
        (const float*)d_in[6],  (const float*)d_in[7],  (const float*)d_in[8],
        (const float*)d_in[9],  (const float*)d_in[10], (const void*)d_in[11],
        (const float*)d_in[12], (const float*)d_in[13], ws, (float*)d_out);
}